// Round 1
// baseline (1403.828 us; speedup 1.0000x reference)
//
#include <hip/hip_runtime.h>
#include <math.h>

// ---------------------------------------------------------------------------
// SimpleGNN (4-layer GCN + mean pool + sigmoid) on MI355X.
// Strategy:
//   - CSR build per call (deterministic work): histogram(dst) -> scan -> scatter
//   - layer1: aggregate 6-dim x first, THEN GEMM (agg(xW) == agg(x)W)
//   - layers 2,3: f32 GEMM (W in LDS) then CSR gather-aggregate (no atomics)
//   - layer4: project to 1-dim, aggregate scalars, pool, sigmoid
// ---------------------------------------------------------------------------

__global__ void hist_kernel(const int* __restrict__ dst, int* __restrict__ counts, int e) {
    int i = blockIdx.x * 256 + threadIdx.x;
    if (i < e) atomicAdd(&counts[dst[i]], 1);
}

__global__ void dinv_kernel(const int* __restrict__ counts, float* __restrict__ dinv, int n) {
    int i = blockIdx.x * 256 + threadIdx.x;
    if (i < n) dinv[i] = rsqrtf((float)counts[i] + 1.0f);
}

// single-block chunked exclusive scan: rowptr[0]=0, rowptr[i+1]=inclusive(counts[0..i])
__global__ void scan_kernel(const int* __restrict__ counts, int* __restrict__ rowptr, int n) {
    __shared__ int warp_sums[16];
    __shared__ int carry_s;
    const int tid  = threadIdx.x;            // 1024 threads
    const int lane = tid & 63, wid = tid >> 6;
    if (tid == 0) carry_s = 0;
    __syncthreads();
    for (int base = 0; base < n; base += 1024) {
        int i = base + tid;
        int v = (i < n) ? counts[i] : 0;
        int x = v;
        #pragma unroll
        for (int off = 1; off < 64; off <<= 1) {
            int y = __shfl_up(x, off);
            if (lane >= off) x += y;
        }
        if (lane == 63) warp_sums[wid] = x;
        __syncthreads();
        if (wid == 0) {
            int s = (lane < 16) ? warp_sums[lane] : 0;
            #pragma unroll
            for (int off = 1; off < 16; off <<= 1) {
                int y = __shfl_up(s, off);
                if (lane >= off) s += y;
            }
            if (lane < 16) warp_sums[lane] = s;
        }
        __syncthreads();
        int carry = carry_s;
        int woff  = (wid > 0) ? warp_sums[wid - 1] : 0;
        int incl  = carry + woff + x;
        if (i < n) rowptr[i + 1] = incl;
        __syncthreads();
        if (tid == 1023) carry_s = incl;
        __syncthreads();
    }
    if (tid == 0) rowptr[0] = 0;
}

__global__ void scatter_kernel(const int* __restrict__ src, const int* __restrict__ dst,
                               const int* __restrict__ rowptr, int* __restrict__ cursor,
                               int* __restrict__ colarr, int e) {
    int i = blockIdx.x * 256 + threadIdx.x;
    if (i < e) {
        int d = dst[i];
        int pos = rowptr[d] + atomicAdd(&cursor[d], 1);
        colarr[pos] = src[i];
    }
}

// aggregate 6-dim input features: ax[i] = dinv[i]*sum_{e:dst=i} x[src]*dinv[src] + x[i]*dinv[i]^2
__global__ void aggx_kernel(const float* __restrict__ x, const int* __restrict__ rowptr,
                            const int* __restrict__ colarr, const float* __restrict__ dinv,
                            float* __restrict__ ax, int n) {
    int i = blockIdx.x * 256 + threadIdx.x;
    if (i >= n) return;
    float di = dinv[i];
    float a0 = 0, a1 = 0, a2 = 0, a3 = 0, a4 = 0, a5 = 0;
    int beg = rowptr[i], end = rowptr[i + 1];
    for (int e = beg; e < end; ++e) {
        int s = colarr[e];
        float w = dinv[s];
        const float* xr = x + (size_t)s * 6;
        a0 += xr[0] * w; a1 += xr[1] * w; a2 += xr[2] * w;
        a3 += xr[3] * w; a4 += xr[4] * w; a5 += xr[5] * w;
    }
    const float* xi = x + (size_t)i * 6;
    float d2 = di * di;
    float* o = ax + (size_t)i * 6;
    o[0] = a0 * di + xi[0] * d2;
    o[1] = a1 * di + xi[1] * d2;
    o[2] = a2 * di + xi[2] * d2;
    o[3] = a3 * di + xi[3] * d2;
    o[4] = a4 * di + xi[4] * d2;
    o[5] = a5 * di + xi[5] * d2;
}

// h1 = relu(ax @ W1 + b1)   (6 -> 128); thread = one (node, col)
__global__ __launch_bounds__(256) void gemm1_kernel(const float* __restrict__ ax,
                                                    const float* __restrict__ W1,
                                                    const float* __restrict__ b1,
                                                    float* __restrict__ h1, int n) {
    __shared__ float Wl[6 * 128];
    __shared__ float bl[128];
    for (int i = threadIdx.x; i < 6 * 128; i += 256) Wl[i] = W1[i];
    if (threadIdx.x < 128) bl[threadIdx.x] = b1[threadIdx.x];
    __syncthreads();
    long long gid = (long long)blockIdx.x * 256 + threadIdx.x;
    int node = (int)(gid >> 7), c = (int)(gid & 127);
    if (node >= n) return;
    const float* ar = ax + (size_t)node * 6;
    float acc = bl[c];
    #pragma unroll
    for (int k = 0; k < 6; ++k) acc += ar[k] * Wl[k * 128 + c];
    h1[(size_t)node * 128 + c] = fmaxf(acc, 0.0f);
}

// out = h @ W (128x128), W staged in LDS; one wave per node, 2 cols/lane
#define GEMM_TN 32
__global__ __launch_bounds__(256) void gemm128_kernel(const float* __restrict__ h,
                                                      const float* __restrict__ W,
                                                      float* __restrict__ out, int n) {
    __shared__ float Wl[128 * 128];
    {
        const float4* Wv = (const float4*)W;
        float4* Wlv = (float4*)Wl;
        for (int i = threadIdx.x; i < 128 * 128 / 4; i += 256) Wlv[i] = Wv[i];
    }
    __syncthreads();
    const int wid = threadIdx.x >> 6, lane = threadIdx.x & 63;
    const int node0 = blockIdx.x * GEMM_TN;
    for (int nn = wid; nn < GEMM_TN; nn += 4) {
        int node = node0 + nn;
        if (node >= n) break;                       // wave-uniform
        const float2 my = ((const float2*)(h + (size_t)node * 128))[lane];
        float acc0 = 0.f, acc1 = 0.f;
        #pragma unroll
        for (int k2 = 0; k2 < 64; ++k2) {
            float hx = __shfl(my.x, k2);
            float hy = __shfl(my.y, k2);
            float2 w0 = ((const float2*)(Wl + (2 * k2) * 128))[lane];
            float2 w1 = ((const float2*)(Wl + (2 * k2 + 1) * 128))[lane];
            acc0 += hx * w0.x + hy * w1.x;
            acc1 += hx * w0.y + hy * w1.y;
        }
        ((float2*)(out + (size_t)node * 128))[lane] = make_float2(acc0, acc1);
    }
}

// out[i] = dinv[i]*sum_{e:dst=i} hp[src]*dinv[src] + hp[i]*dinv[i]^2 + b ; optional relu
__global__ __launch_bounds__(256) void agg128_kernel(const float* __restrict__ hp,
                                                     const int* __restrict__ rowptr,
                                                     const int* __restrict__ colarr,
                                                     const float* __restrict__ dinv,
                                                     const float* __restrict__ bias,
                                                     float* __restrict__ out, int n, int relu) {
    int node = blockIdx.x * 4 + (threadIdx.x >> 6);
    if (node >= n) return;
    const int lane = threadIdx.x & 63;
    const int beg = rowptr[node], end = rowptr[node + 1];
    const float di = dinv[node];
    float ax = 0.f, ay = 0.f;
    for (int e = beg; e < end; ++e) {
        int s = colarr[e];
        float w = dinv[s];
        float2 v = ((const float2*)(hp + (size_t)s * 128))[lane];
        ax += v.x * w;
        ay += v.y * w;
    }
    float2 sv = ((const float2*)(hp + (size_t)node * 128))[lane];
    float2 b  = ((const float2*)bias)[lane];
    float d2 = di * di;
    float ox = ax * di + sv.x * d2 + b.x;
    float oy = ay * di + sv.y * d2 + b.y;
    if (relu) { ox = fmaxf(ox, 0.f); oy = fmaxf(oy, 0.f); }
    ((float2*)(out + (size_t)node * 128))[lane] = make_float2(ox, oy);
}

// t[i] = dot(h[i,:], W4[:,0]) ; one wave per node
__global__ void head_kernel(const float* __restrict__ h, const float* __restrict__ W4,
                            float* __restrict__ t, int n) {
    int node = blockIdx.x * 4 + (threadIdx.x >> 6);
    if (node >= n) return;
    int lane = threadIdx.x & 63;
    float2 v = ((const float2*)(h + (size_t)node * 128))[lane];
    float2 w = ((const float2*)W4)[lane];
    float p = v.x * w.x + v.y * w.y;
    #pragma unroll
    for (int off = 32; off; off >>= 1) p += __shfl_xor(p, off);
    if (lane == 0) t[node] = p;
}

__global__ void aggs_kernel(const float* __restrict__ t, const int* __restrict__ rowptr,
                            const int* __restrict__ colarr, const float* __restrict__ dinv,
                            const float* __restrict__ b4, float* __restrict__ s, int n) {
    int i = blockIdx.x * 256 + threadIdx.x;
    if (i >= n) return;
    float di = dinv[i];
    float acc = 0.f;
    int beg = rowptr[i], end = rowptr[i + 1];
    for (int e = beg; e < end; ++e) {
        int s0 = colarr[e];
        acc += t[s0] * dinv[s0];
    }
    s[i] = acc * di + t[i] * di * di + b4[0];
}

__global__ void pool_kernel(const float* __restrict__ s, const int* __restrict__ batch,
                            float* __restrict__ pooled, float* __restrict__ cnt, int n) {
    int i = blockIdx.x * 256 + threadIdx.x;
    if (i >= n) return;
    int g = batch[i];
    atomicAdd(&pooled[g], s[i]);
    atomicAdd(&cnt[g], 1.0f);
}

__global__ void final_kernel(const float* __restrict__ pooled, const float* __restrict__ cnt,
                             float* __restrict__ out, int ng) {
    int g = threadIdx.x;
    if (g >= ng) return;
    float c = fmaxf(cnt[g], 1.0f);
    float v = pooled[g] / c;
    out[g] = 1.0f / (1.0f + expf(-v));
}

extern "C" void kernel_launch(void* const* d_in, const int* in_sizes, int n_in,
                              void* d_out, int out_size, void* d_ws, size_t ws_size,
                              hipStream_t stream) {
    const float* x    = (const float*)d_in[0];
    const int*   eidx = (const int*)d_in[1];
    const int*   batch= (const int*)d_in[2];
    const float* W1 = (const float*)d_in[3];
    const float* b1 = (const float*)d_in[4];
    const float* W2 = (const float*)d_in[5];
    const float* b2 = (const float*)d_in[6];
    const float* W3 = (const float*)d_in[7];
    const float* b3 = (const float*)d_in[8];
    const float* W4 = (const float*)d_in[9];
    const float* b4 = (const float*)d_in[10];

    const int n  = in_sizes[0] / 6;
    const int e  = in_sizes[1] / 2;
    const int ng = out_size;
    const int* src = eidx;
    const int* dst = eidx + e;

    // workspace layout
    char* ws = (char*)d_ws;
    float* bufA   = (float*)ws; ws += (size_t)n * 128 * 4;
    float* bufB   = (float*)ws; ws += (size_t)n * 128 * 4;
    int*   colarr = (int*)ws;   ws += (size_t)e * 4;
    int*   rowptr = (int*)ws;   ws += ((size_t)n + 4) * 4;
    float* dinv   = (float*)ws; ws += (size_t)n * 4;
    int*   counts = (int*)ws;   ws += (size_t)n * 4;   // later reused as t
    int*   cursor = (int*)ws;   ws += (size_t)n * 4;   // later reused as s
    float* pooled = (float*)ws; ws += 1024;
    float* cnt    = (float*)ws; ws += 1024;

    float* ax = bufB;            // [n,6] lives in bufB until gemm1 consumes it
    float* t  = (float*)counts;  // [n] after CSR build
    float* sv = (float*)cursor;  // [n] after CSR build

    const int eb = (e + 255) / 256;
    const int nb = (n + 255) / 256;
    const int nw = (n + 3) / 4;  // wave-per-node kernels, 4 waves/block

    // ---- CSR build ----
    hipMemsetAsync(counts, 0, (size_t)n * 4, stream);
    hist_kernel<<<eb, 256, 0, stream>>>(dst, counts, e);
    dinv_kernel<<<nb, 256, 0, stream>>>(counts, dinv, n);
    scan_kernel<<<1, 1024, 0, stream>>>(counts, rowptr, n);
    hipMemsetAsync(cursor, 0, (size_t)n * 4, stream);
    scatter_kernel<<<eb, 256, 0, stream>>>(src, dst, rowptr, cursor, colarr, e);

    // ---- layer 1: aggregate x (6-dim) then GEMM ----
    aggx_kernel<<<nb, 256, 0, stream>>>(x, rowptr, colarr, dinv, ax, n);
    gemm1_kernel<<<(int)(((long long)n * 128 + 255) / 256), 256, 0, stream>>>(ax, W1, b1, bufA, n);

    // ---- layer 2 ----
    gemm128_kernel<<<(n + GEMM_TN - 1) / GEMM_TN, 256, 0, stream>>>(bufA, W2, bufB, n);
    agg128_kernel<<<nw, 256, 0, stream>>>(bufB, rowptr, colarr, dinv, b2, bufA, n, 1);

    // ---- layer 3 ----
    gemm128_kernel<<<(n + GEMM_TN - 1) / GEMM_TN, 256, 0, stream>>>(bufA, W3, bufB, n);
    agg128_kernel<<<nw, 256, 0, stream>>>(bufB, rowptr, colarr, dinv, b3, bufA, n, 1);

    // ---- layer 4: project to scalar, aggregate, pool, sigmoid ----
    head_kernel<<<nw, 256, 0, stream>>>(bufA, W4, t, n);
    aggs_kernel<<<nb, 256, 0, stream>>>(t, rowptr, colarr, dinv, b4, sv, n);

    hipMemsetAsync(pooled, 0, 2048, stream);
    pool_kernel<<<nb, 256, 0, stream>>>(sv, batch, pooled, cnt, n);
    final_kernel<<<1, 256, 0, stream>>>(pooled, cnt, (float*)d_out, ng);
}

// Round 2
// 885.115 us; speedup vs baseline: 1.5860x; 1.5860x over previous
//
#include <hip/hip_runtime.h>
#include <math.h>

// ---------------------------------------------------------------------------
// SimpleGNN (4-layer GCN + mean pool + sigmoid) on MI355X.
//   - CSR build per call: histogram(dst) -> block scan (int4) -> scatter
//   - norm factored: GEMM epilogue scales rows by dinv[row], so aggregation
//     is a pure gather-sum: out = dinv[i]*(sum_{s in N(i)} g[s] + g[i]) + b
//   - layer1 reassociated: aggregate 6-dim x (prescaled by dinv) then GEMM
//   - layers 2,3: register-tiled f32 GEMM (64 nodes/block, 8x4 per thread)
//   - layer4: project to scalar (x dinv), aggregate scalars, pool, sigmoid
// ---------------------------------------------------------------------------

__global__ void hist_kernel(const int* __restrict__ dst, int* __restrict__ counts, int e) {
    int i = blockIdx.x * 256 + threadIdx.x;
    if (i < e) atomicAdd(&counts[dst[i]], 1);
}

__global__ void dinv_kernel(const int* __restrict__ counts, float* __restrict__ dinv, int n) {
    int i = blockIdx.x * 256 + threadIdx.x;
    if (i < n) dinv[i] = rsqrtf((float)counts[i] + 1.0f);
}

// single-block chunked exclusive scan, 4 items/thread (chunk = 4096)
__global__ void scan_kernel(const int* __restrict__ counts, int* __restrict__ rowptr, int n) {
    __shared__ int wsum[16];
    __shared__ int carry_s;
    const int tid  = threadIdx.x;            // 1024 threads
    const int lane = tid & 63, wid = tid >> 6;
    if (tid == 0) carry_s = 0;
    __syncthreads();
    const int nchunk = (n + 4095) >> 12;
    for (int c = 0; c < nchunk; ++c) {
        int i0 = (c << 12) + tid * 4;
        int4 v = make_int4(0, 0, 0, 0);
        if (i0 + 3 < n) {
            v = *(const int4*)(counts + i0);
        } else {
            if (i0     < n) v.x = counts[i0];
            if (i0 + 1 < n) v.y = counts[i0 + 1];
            if (i0 + 2 < n) v.z = counts[i0 + 2];
            if (i0 + 3 < n) v.w = counts[i0 + 3];
        }
        int s1 = v.x, s2 = s1 + v.y, s3 = s2 + v.z, s4 = s3 + v.w;
        int x = s4;
        #pragma unroll
        for (int off = 1; off < 64; off <<= 1) {
            int y = __shfl_up(x, off);
            if (lane >= off) x += y;
        }
        if (lane == 63) wsum[wid] = x;
        __syncthreads();
        if (wid == 0) {
            int s = (lane < 16) ? wsum[lane] : 0;
            #pragma unroll
            for (int off = 1; off < 16; off <<= 1) {
                int y = __shfl_up(s, off);
                if (lane >= off) s += y;
            }
            if (lane < 16) wsum[lane] = s;
        }
        __syncthreads();
        int carry = carry_s + ((wid > 0) ? wsum[wid - 1] : 0);
        int excl  = carry + x - s4;   // exclusive prefix for this thread's items
        if (i0     < n) rowptr[i0 + 1] = excl + s1;
        if (i0 + 1 < n) rowptr[i0 + 2] = excl + s2;
        if (i0 + 2 < n) rowptr[i0 + 3] = excl + s3;
        if (i0 + 3 < n) rowptr[i0 + 4] = excl + s4;
        __syncthreads();
        if (tid == 1023) carry_s = carry + x;
        __syncthreads();
    }
    if (tid == 0) rowptr[0] = 0;
}

__global__ void scatter_kernel(const int* __restrict__ src, const int* __restrict__ dst,
                               const int* __restrict__ rowptr, int* __restrict__ cursor,
                               int* __restrict__ colarr, int e) {
    int i = blockIdx.x * 256 + threadIdx.x;
    if (i < e) {
        int d = dst[i];
        int pos = rowptr[d] + atomicAdd(&cursor[d], 1);
        colarr[pos] = src[i];
    }
}

// xs[i,c] = x[i,c] * dinv[i]
__global__ void xscale_kernel(const float* __restrict__ x, const float* __restrict__ dinv,
                              float* __restrict__ xs, int n) {
    int i = blockIdx.x * 256 + threadIdx.x;
    if (i >= n * 6) return;
    xs[i] = x[i] * dinv[i / 6];
}

// ax[i] = dinv[i] * ( sum_{s in N(i)} xs[s] + xs[i] )    (6-dim)
__global__ void aggx_kernel(const float* __restrict__ xs, const int* __restrict__ rowptr,
                            const int* __restrict__ colarr, const float* __restrict__ dinv,
                            float* __restrict__ ax, int n) {
    int i = blockIdx.x * 256 + threadIdx.x;
    if (i >= n) return;
    float a0 = 0, a1 = 0, a2 = 0, a3 = 0, a4 = 0, a5 = 0;
    int beg = rowptr[i], end = rowptr[i + 1];
    for (int e = beg; e < end; ++e) {
        int s = colarr[e];
        const float* xr = xs + (size_t)s * 6;
        a0 += xr[0]; a1 += xr[1]; a2 += xr[2];
        a3 += xr[3]; a4 += xr[4]; a5 += xr[5];
    }
    const float* xi = xs + (size_t)i * 6;
    float di = dinv[i];
    float* o = ax + (size_t)i * 6;
    o[0] = (a0 + xi[0]) * di;
    o[1] = (a1 + xi[1]) * di;
    o[2] = (a2 + xi[2]) * di;
    o[3] = (a3 + xi[3]) * di;
    o[4] = (a4 + xi[4]) * di;
    o[5] = (a5 + xi[5]) * di;
}

// h1 = relu(ax @ W1 + b1)   (6 -> 128); thread = one (node, col)
__global__ __launch_bounds__(256) void gemm1_kernel(const float* __restrict__ ax,
                                                    const float* __restrict__ W1,
                                                    const float* __restrict__ b1,
                                                    float* __restrict__ h1, int n) {
    __shared__ float Wl[6 * 128];
    __shared__ float bl[128];
    for (int i = threadIdx.x; i < 6 * 128; i += 256) Wl[i] = W1[i];
    if (threadIdx.x < 128) bl[threadIdx.x] = b1[threadIdx.x];
    __syncthreads();
    int gid = blockIdx.x * 256 + threadIdx.x;
    int node = gid >> 7, c = gid & 127;
    if (node >= n) return;
    const float* ar = ax + (size_t)node * 6;
    float acc = bl[c];
    #pragma unroll
    for (int k = 0; k < 6; ++k) acc += ar[k] * Wl[k * 128 + c];
    h1[(size_t)node * 128 + c] = fmaxf(acc, 0.0f);
}

// out[node,:] = (h[node,:] @ W) * dinv[node]
// register-tiled: 64 nodes/block, 256 threads, each 8 nodes x 4 cols
#define GN 64
__global__ __launch_bounds__(256, 4) void gemm128_reg(const float* __restrict__ h,
                                                      const float* __restrict__ W,
                                                      const float* __restrict__ dinv,
                                                      float* __restrict__ out, int n) {
    __shared__ float Hs[GN][132];   // +4 pad: 16B-aligned rows, conflict-free reads
    const int node0 = blockIdx.x * GN;
    {
        int r  = threadIdx.x >> 5;
        int c4 = (threadIdx.x & 31) * 4;
        #pragma unroll
        for (int rr = r; rr < GN; rr += 8) {
            int node = node0 + rr;
            float4 v = make_float4(0.f, 0.f, 0.f, 0.f);
            if (node < n) v = *(const float4*)(h + (size_t)node * 128 + c4);
            *(float4*)&Hs[rr][c4] = v;
        }
    }
    __syncthreads();
    const int tx = threadIdx.x & 31;   // col group: cols 4*tx .. 4*tx+3
    const int ty = threadIdx.x >> 5;   // node group: nodes ty*8 .. ty*8+7
    float4 acc[8];
    #pragma unroll
    for (int i = 0; i < 8; ++i) acc[i] = make_float4(0.f, 0.f, 0.f, 0.f);
    const float4* Wv = (const float4*)W;   // W row k, col group tx -> Wv[k*32+tx]
    #pragma unroll 4
    for (int k4 = 0; k4 < 32; ++k4) {
        float4 w0 = Wv[(4 * k4 + 0) * 32 + tx];
        float4 w1 = Wv[(4 * k4 + 1) * 32 + tx];
        float4 w2 = Wv[(4 * k4 + 2) * 32 + tx];
        float4 w3 = Wv[(4 * k4 + 3) * 32 + tx];
        #pragma unroll
        for (int i = 0; i < 8; ++i) {
            float4 hv = *(const float4*)&Hs[ty * 8 + i][4 * k4];
            acc[i].x += hv.x * w0.x + hv.y * w1.x + hv.z * w2.x + hv.w * w3.x;
            acc[i].y += hv.x * w0.y + hv.y * w1.y + hv.z * w2.y + hv.w * w3.y;
            acc[i].z += hv.x * w0.z + hv.y * w1.z + hv.z * w2.z + hv.w * w3.z;
            acc[i].w += hv.x * w0.w + hv.y * w1.w + hv.z * w2.w + hv.w * w3.w;
        }
    }
    #pragma unroll
    for (int i = 0; i < 8; ++i) {
        int node = node0 + ty * 8 + i;
        if (node < n) {
            float dv = dinv[node];
            float4 o = make_float4(acc[i].x * dv, acc[i].y * dv, acc[i].z * dv, acc[i].w * dv);
            *(float4*)(out + (size_t)node * 128 + 4 * tx) = o;
        }
    }
}

// out[i] = relu_opt( dinv[i]*( sum_{s in N(i)} g[s] + g[i] ) + b )   (128-dim)
__global__ __launch_bounds__(256) void agg128_kernel(const float* __restrict__ g,
                                                     const int* __restrict__ rowptr,
                                                     const int* __restrict__ colarr,
                                                     const float* __restrict__ dinv,
                                                     const float* __restrict__ bias,
                                                     float* __restrict__ out, int n, int relu) {
    int node = blockIdx.x * 4 + (threadIdx.x >> 6);
    if (node >= n) return;
    const int lane = threadIdx.x & 63;
    const float2* gl = (const float2*)g + lane;   // row s -> gl[s*64]
    const int beg = rowptr[node], end = rowptr[node + 1];
    float ax = 0.f, ay = 0.f;
    int e = beg;
    for (; e + 3 < end; e += 4) {
        int s0 = colarr[e], s1 = colarr[e + 1], s2 = colarr[e + 2], s3 = colarr[e + 3];
        float2 v0 = gl[(size_t)s0 * 64];
        float2 v1 = gl[(size_t)s1 * 64];
        float2 v2 = gl[(size_t)s2 * 64];
        float2 v3 = gl[(size_t)s3 * 64];
        ax += (v0.x + v1.x) + (v2.x + v3.x);
        ay += (v0.y + v1.y) + (v2.y + v3.y);
    }
    for (; e < end; ++e) {
        float2 v = gl[(size_t)colarr[e] * 64];
        ax += v.x; ay += v.y;
    }
    float2 sv = gl[(size_t)node * 64];
    float2 b  = ((const float2*)bias)[lane];
    float di  = dinv[node];
    float ox = (ax + sv.x) * di + b.x;
    float oy = (ay + sv.y) * di + b.y;
    if (relu) { ox = fmaxf(ox, 0.f); oy = fmaxf(oy, 0.f); }
    ((float2*)(out + (size_t)node * 128))[lane] = make_float2(ox, oy);
}

// t[i] = dot(h[i,:], W4[:,0]) * dinv[i] ; one wave per node
__global__ void head_kernel(const float* __restrict__ h, const float* __restrict__ W4,
                            const float* __restrict__ dinv, float* __restrict__ t, int n) {
    int node = blockIdx.x * 4 + (threadIdx.x >> 6);
    if (node >= n) return;
    int lane = threadIdx.x & 63;
    float2 v = ((const float2*)(h + (size_t)node * 128))[lane];
    float2 w = ((const float2*)W4)[lane];
    float p = v.x * w.x + v.y * w.y;
    #pragma unroll
    for (int off = 32; off; off >>= 1) p += __shfl_xor(p, off);
    if (lane == 0) t[node] = p * dinv[node];
}

// s[i] = dinv[i]*( sum t[s] + t[i] ) + b4
__global__ void aggs_kernel(const float* __restrict__ t, const int* __restrict__ rowptr,
                            const int* __restrict__ colarr, const float* __restrict__ dinv,
                            const float* __restrict__ b4, float* __restrict__ s, int n) {
    int i = blockIdx.x * 256 + threadIdx.x;
    if (i >= n) return;
    float acc = 0.f;
    int beg = rowptr[i], end = rowptr[i + 1];
    int e = beg;
    for (; e + 3 < end; e += 4) {
        acc += (t[colarr[e]] + t[colarr[e + 1]]) + (t[colarr[e + 2]] + t[colarr[e + 3]]);
    }
    for (; e < end; ++e) acc += t[colarr[e]];
    s[i] = (acc + t[i]) * dinv[i] + b4[0];
}

__global__ void pool_kernel(const float* __restrict__ s, const int* __restrict__ batch,
                            float* __restrict__ pooled, float* __restrict__ cnt, int n) {
    int i = blockIdx.x * 256 + threadIdx.x;
    if (i >= n) return;
    int g = batch[i];
    atomicAdd(&pooled[g], s[i]);
    atomicAdd(&cnt[g], 1.0f);
}

__global__ void final_kernel(const float* __restrict__ pooled, const float* __restrict__ cnt,
                             float* __restrict__ out, int ng) {
    int g = threadIdx.x;
    if (g >= ng) return;
    float c = fmaxf(cnt[g], 1.0f);
    float v = pooled[g] / c;
    out[g] = 1.0f / (1.0f + expf(-v));
}

extern "C" void kernel_launch(void* const* d_in, const int* in_sizes, int n_in,
                              void* d_out, int out_size, void* d_ws, size_t ws_size,
                              hipStream_t stream) {
    const float* x    = (const float*)d_in[0];
    const int*   eidx = (const int*)d_in[1];
    const int*   batch= (const int*)d_in[2];
    const float* W1 = (const float*)d_in[3];
    const float* b1 = (const float*)d_in[4];
    const float* W2 = (const float*)d_in[5];
    const float* b2 = (const float*)d_in[6];
    const float* W3 = (const float*)d_in[7];
    const float* b3 = (const float*)d_in[8];
    const float* W4 = (const float*)d_in[9];
    const float* b4 = (const float*)d_in[10];

    const int n  = in_sizes[0] / 6;
    const int e  = in_sizes[1] / 2;
    const int ng = out_size;
    const int* src = eidx;
    const int* dst = eidx + e;

    // workspace layout (same footprint as R1)
    char* ws = (char*)d_ws;
    float* bufA   = (float*)ws; ws += (size_t)n * 128 * 4;
    float* bufB   = (float*)ws; ws += (size_t)n * 128 * 4;
    int*   colarr = (int*)ws;   ws += (size_t)e * 4;
    int*   rowptr = (int*)ws;   ws += ((size_t)n + 4) * 4;
    float* dinv   = (float*)ws; ws += (size_t)n * 4;
    int*   counts = (int*)ws;   ws += (size_t)n * 4;   // later reused as t
    int*   cursor = (int*)ws;   ws += (size_t)n * 4;   // later reused as s
    float* pooled = (float*)ws; ws += 1024;
    float* cnt    = (float*)ws; ws += 1024;

    float* xs = bufA;            // [n,6] prescaled x (bufA until gemm1 writes h1)
    float* ax = bufB;            // [n,6] aggregated (bufB until gemm1 consumes it)
    float* t  = (float*)counts;  // [n] after CSR build
    float* sv = (float*)cursor;  // [n] after CSR build

    const int eb = (e + 255) / 256;
    const int nb = (n + 255) / 256;
    const int nw = (n + 3) / 4;       // wave-per-node kernels, 4 waves/block
    const int gb = (n + GN - 1) / GN; // gemm128_reg blocks

    // ---- CSR build ----
    hipMemsetAsync(counts, 0, (size_t)n * 4, stream);
    hist_kernel<<<eb, 256, 0, stream>>>(dst, counts, e);
    dinv_kernel<<<nb, 256, 0, stream>>>(counts, dinv, n);
    scan_kernel<<<1, 1024, 0, stream>>>(counts, rowptr, n);
    hipMemsetAsync(cursor, 0, (size_t)n * 4, stream);
    scatter_kernel<<<eb, 256, 0, stream>>>(src, dst, rowptr, cursor, colarr, e);

    // ---- layer 1: prescale x, aggregate (6-dim), then GEMM ----
    xscale_kernel<<<(n * 6 + 255) / 256, 256, 0, stream>>>(x, dinv, xs, n);
    aggx_kernel<<<nb, 256, 0, stream>>>(xs, rowptr, colarr, dinv, ax, n);
    gemm1_kernel<<<(n * 128 + 255) / 256, 256, 0, stream>>>(ax, W1, b1, bufA, n);

    // ---- layer 2 ----
    gemm128_reg<<<gb, 256, 0, stream>>>(bufA, W2, dinv, bufB, n);
    agg128_kernel<<<nw, 256, 0, stream>>>(bufB, rowptr, colarr, dinv, b2, bufA, n, 1);

    // ---- layer 3 ----
    gemm128_reg<<<gb, 256, 0, stream>>>(bufA, W3, dinv, bufB, n);
    agg128_kernel<<<nw, 256, 0, stream>>>(bufB, rowptr, colarr, dinv, b3, bufA, n, 1);

    // ---- layer 4: project to scalar, aggregate, pool, sigmoid ----
    head_kernel<<<nw, 256, 0, stream>>>(bufA, W4, dinv, t, n);
    aggs_kernel<<<nb, 256, 0, stream>>>(t, rowptr, colarr, dinv, b4, sv, n);

    hipMemsetAsync(pooled, 0, 2048, stream);
    pool_kernel<<<nb, 256, 0, stream>>>(sv, batch, pooled, cnt, n);
    final_kernel<<<1, 256, 0, stream>>>(pooled, cnt, (float*)d_out, ng);
}

// Round 3
// 695.815 us; speedup vs baseline: 2.0175x; 1.2721x over previous
//
#include <hip/hip_runtime.h>
#include <math.h>

// ---------------------------------------------------------------------------
// SimpleGNN (4-layer GCN + mean pool + sigmoid) on MI355X.
//   - CSR build per call: histogram(dst) -> block scan (int4) -> scatter
//   - norm factored: GEMM epilogue scales rows by dinv[row], so aggregation
//     is a pure gather-sum: out = dinv[i]*(sum_{s in N(i)} g[s] + g[i]) + b
//   - layer1 reassociated: aggregate 6-dim x (prescaled by dinv) then GEMM
//   - layers 2,3: register-tiled f32 GEMM (64 nodes/block, 8x4 per thread)
//   - layer4: project to scalar (x dinv), aggregate scalars
//   - pool: batch is SORTED -> segment bounds + per-graph wave reduction
//     (R2's atomicAdd pool serialized on sorted batch: 202 us -> ~4 us)
// ---------------------------------------------------------------------------

__global__ void hist_kernel(const int* __restrict__ dst, int* __restrict__ counts, int e) {
    int i = blockIdx.x * 256 + threadIdx.x;
    if (i < e) atomicAdd(&counts[dst[i]], 1);
}

__global__ void dinv_kernel(const int* __restrict__ counts, float* __restrict__ dinv, int n) {
    int i = blockIdx.x * 256 + threadIdx.x;
    if (i < n) dinv[i] = rsqrtf((float)counts[i] + 1.0f);
}

// single-block chunked exclusive scan, 4 items/thread (chunk = 4096)
__global__ void scan_kernel(const int* __restrict__ counts, int* __restrict__ rowptr, int n) {
    __shared__ int wsum[16];
    __shared__ int carry_s;
    const int tid  = threadIdx.x;            // 1024 threads
    const int lane = tid & 63, wid = tid >> 6;
    if (tid == 0) carry_s = 0;
    __syncthreads();
    const int nchunk = (n + 4095) >> 12;
    for (int c = 0; c < nchunk; ++c) {
        int i0 = (c << 12) + tid * 4;
        int4 v = make_int4(0, 0, 0, 0);
        if (i0 + 3 < n) {
            v = *(const int4*)(counts + i0);
        } else {
            if (i0     < n) v.x = counts[i0];
            if (i0 + 1 < n) v.y = counts[i0 + 1];
            if (i0 + 2 < n) v.z = counts[i0 + 2];
            if (i0 + 3 < n) v.w = counts[i0 + 3];
        }
        int s1 = v.x, s2 = s1 + v.y, s3 = s2 + v.z, s4 = s3 + v.w;
        int x = s4;
        #pragma unroll
        for (int off = 1; off < 64; off <<= 1) {
            int y = __shfl_up(x, off);
            if (lane >= off) x += y;
        }
        if (lane == 63) wsum[wid] = x;
        __syncthreads();
        if (wid == 0) {
            int s = (lane < 16) ? wsum[lane] : 0;
            #pragma unroll
            for (int off = 1; off < 16; off <<= 1) {
                int y = __shfl_up(s, off);
                if (lane >= off) s += y;
            }
            if (lane < 16) wsum[lane] = s;
        }
        __syncthreads();
        int carry = carry_s + ((wid > 0) ? wsum[wid - 1] : 0);
        int excl  = carry + x - s4;   // exclusive prefix for this thread's items
        if (i0     < n) rowptr[i0 + 1] = excl + s1;
        if (i0 + 1 < n) rowptr[i0 + 2] = excl + s2;
        if (i0 + 2 < n) rowptr[i0 + 3] = excl + s3;
        if (i0 + 3 < n) rowptr[i0 + 4] = excl + s4;
        __syncthreads();
        if (tid == 1023) carry_s = carry + x;
        __syncthreads();
    }
    if (tid == 0) rowptr[0] = 0;
}

__global__ void scatter_kernel(const int* __restrict__ src, const int* __restrict__ dst,
                               const int* __restrict__ rowptr, int* __restrict__ cursor,
                               int* __restrict__ colarr, int e) {
    int i = blockIdx.x * 256 + threadIdx.x;
    if (i < e) {
        int d = dst[i];
        int pos = rowptr[d] + atomicAdd(&cursor[d], 1);
        colarr[pos] = src[i];
    }
}

// xs[i,c] = x[i,c] * dinv[i]
__global__ void xscale_kernel(const float* __restrict__ x, const float* __restrict__ dinv,
                              float* __restrict__ xs, int n) {
    int i = blockIdx.x * 256 + threadIdx.x;
    if (i >= n * 6) return;
    xs[i] = x[i] * dinv[i / 6];
}

// ax[i] = dinv[i] * ( sum_{s in N(i)} xs[s] + xs[i] )    (6-dim)
__global__ void aggx_kernel(const float* __restrict__ xs, const int* __restrict__ rowptr,
                            const int* __restrict__ colarr, const float* __restrict__ dinv,
                            float* __restrict__ ax, int n) {
    int i = blockIdx.x * 256 + threadIdx.x;
    if (i >= n) return;
    float a0 = 0, a1 = 0, a2 = 0, a3 = 0, a4 = 0, a5 = 0;
    int beg = rowptr[i], end = rowptr[i + 1];
    for (int e = beg; e < end; ++e) {
        int s = colarr[e];
        const float* xr = xs + (size_t)s * 6;
        a0 += xr[0]; a1 += xr[1]; a2 += xr[2];
        a3 += xr[3]; a4 += xr[4]; a5 += xr[5];
    }
    const float* xi = xs + (size_t)i * 6;
    float di = dinv[i];
    float* o = ax + (size_t)i * 6;
    o[0] = (a0 + xi[0]) * di;
    o[1] = (a1 + xi[1]) * di;
    o[2] = (a2 + xi[2]) * di;
    o[3] = (a3 + xi[3]) * di;
    o[4] = (a4 + xi[4]) * di;
    o[5] = (a5 + xi[5]) * di;
}

// h1 = relu(ax @ W1 + b1)   (6 -> 128); thread = one (node, col)
__global__ __launch_bounds__(256) void gemm1_kernel(const float* __restrict__ ax,
                                                    const float* __restrict__ W1,
                                                    const float* __restrict__ b1,
                                                    float* __restrict__ h1, int n) {
    __shared__ float Wl[6 * 128];
    __shared__ float bl[128];
    for (int i = threadIdx.x; i < 6 * 128; i += 256) Wl[i] = W1[i];
    if (threadIdx.x < 128) bl[threadIdx.x] = b1[threadIdx.x];
    __syncthreads();
    int gid = blockIdx.x * 256 + threadIdx.x;
    int node = gid >> 7, c = gid & 127;
    if (node >= n) return;
    const float* ar = ax + (size_t)node * 6;
    float acc = bl[c];
    #pragma unroll
    for (int k = 0; k < 6; ++k) acc += ar[k] * Wl[k * 128 + c];
    h1[(size_t)node * 128 + c] = fmaxf(acc, 0.0f);
}

// out[node,:] = (h[node,:] @ W) * dinv[node]
// register-tiled: 64 nodes/block, 256 threads, each 8 nodes x 4 cols
#define GN 64
__global__ __launch_bounds__(256, 4) void gemm128_reg(const float* __restrict__ h,
                                                      const float* __restrict__ W,
                                                      const float* __restrict__ dinv,
                                                      float* __restrict__ out, int n) {
    __shared__ float Hs[GN][132];   // +4 pad: 16B-aligned rows, conflict-free reads
    const int node0 = blockIdx.x * GN;
    {
        int r  = threadIdx.x >> 5;
        int c4 = (threadIdx.x & 31) * 4;
        #pragma unroll
        for (int rr = r; rr < GN; rr += 8) {
            int node = node0 + rr;
            float4 v = make_float4(0.f, 0.f, 0.f, 0.f);
            if (node < n) v = *(const float4*)(h + (size_t)node * 128 + c4);
            *(float4*)&Hs[rr][c4] = v;
        }
    }
    __syncthreads();
    const int tx = threadIdx.x & 31;   // col group: cols 4*tx .. 4*tx+3
    const int ty = threadIdx.x >> 5;   // node group: nodes ty*8 .. ty*8+7
    float4 acc[8];
    #pragma unroll
    for (int i = 0; i < 8; ++i) acc[i] = make_float4(0.f, 0.f, 0.f, 0.f);
    const float4* Wv = (const float4*)W;   // W row k, col group tx -> Wv[k*32+tx]
    #pragma unroll 4
    for (int k4 = 0; k4 < 32; ++k4) {
        float4 w0 = Wv[(4 * k4 + 0) * 32 + tx];
        float4 w1 = Wv[(4 * k4 + 1) * 32 + tx];
        float4 w2 = Wv[(4 * k4 + 2) * 32 + tx];
        float4 w3 = Wv[(4 * k4 + 3) * 32 + tx];
        #pragma unroll
        for (int i = 0; i < 8; ++i) {
            float4 hv = *(const float4*)&Hs[ty * 8 + i][4 * k4];
            acc[i].x += hv.x * w0.x + hv.y * w1.x + hv.z * w2.x + hv.w * w3.x;
            acc[i].y += hv.x * w0.y + hv.y * w1.y + hv.z * w2.y + hv.w * w3.y;
            acc[i].z += hv.x * w0.z + hv.y * w1.z + hv.z * w2.z + hv.w * w3.z;
            acc[i].w += hv.x * w0.w + hv.y * w1.w + hv.z * w2.w + hv.w * w3.w;
        }
    }
    #pragma unroll
    for (int i = 0; i < 8; ++i) {
        int node = node0 + ty * 8 + i;
        if (node < n) {
            float dv = dinv[node];
            float4 o = make_float4(acc[i].x * dv, acc[i].y * dv, acc[i].z * dv, acc[i].w * dv);
            *(float4*)(out + (size_t)node * 128 + 4 * tx) = o;
        }
    }
}

// out[i] = relu_opt( dinv[i]*( sum_{s in N(i)} g[s] + g[i] ) + b )   (128-dim)
__global__ __launch_bounds__(256) void agg128_kernel(const float* __restrict__ g,
                                                     const int* __restrict__ rowptr,
                                                     const int* __restrict__ colarr,
                                                     const float* __restrict__ dinv,
                                                     const float* __restrict__ bias,
                                                     float* __restrict__ out, int n, int relu) {
    int node = blockIdx.x * 4 + (threadIdx.x >> 6);
    if (node >= n) return;
    const int lane = threadIdx.x & 63;
    const float2* gl = (const float2*)g + lane;   // row s -> gl[s*64]
    const int beg = rowptr[node], end = rowptr[node + 1];
    float ax = 0.f, ay = 0.f;
    int e = beg;
    for (; e + 3 < end; e += 4) {
        int s0 = colarr[e], s1 = colarr[e + 1], s2 = colarr[e + 2], s3 = colarr[e + 3];
        float2 v0 = gl[(size_t)s0 * 64];
        float2 v1 = gl[(size_t)s1 * 64];
        float2 v2 = gl[(size_t)s2 * 64];
        float2 v3 = gl[(size_t)s3 * 64];
        ax += (v0.x + v1.x) + (v2.x + v3.x);
        ay += (v0.y + v1.y) + (v2.y + v3.y);
    }
    for (; e < end; ++e) {
        float2 v = gl[(size_t)colarr[e] * 64];
        ax += v.x; ay += v.y;
    }
    float2 sv = gl[(size_t)node * 64];
    float2 b  = ((const float2*)bias)[lane];
    float di  = dinv[node];
    float ox = (ax + sv.x) * di + b.x;
    float oy = (ay + sv.y) * di + b.y;
    if (relu) { ox = fmaxf(ox, 0.f); oy = fmaxf(oy, 0.f); }
    ((float2*)(out + (size_t)node * 128))[lane] = make_float2(ox, oy);
}

// t[i] = dot(h[i,:], W4[:,0]) * dinv[i] ; one wave per node
__global__ void head_kernel(const float* __restrict__ h, const float* __restrict__ W4,
                            const float* __restrict__ dinv, float* __restrict__ t, int n) {
    int node = blockIdx.x * 4 + (threadIdx.x >> 6);
    if (node >= n) return;
    int lane = threadIdx.x & 63;
    float2 v = ((const float2*)(h + (size_t)node * 128))[lane];
    float2 w = ((const float2*)W4)[lane];
    float p = v.x * w.x + v.y * w.y;
    #pragma unroll
    for (int off = 32; off; off >>= 1) p += __shfl_xor(p, off);
    if (lane == 0) t[node] = p * dinv[node];
}

// s[i] = dinv[i]*( sum t[s] + t[i] ) + b4
__global__ void aggs_kernel(const float* __restrict__ t, const int* __restrict__ rowptr,
                            const int* __restrict__ colarr, const float* __restrict__ dinv,
                            const float* __restrict__ b4, float* __restrict__ s, int n) {
    int i = blockIdx.x * 256 + threadIdx.x;
    if (i >= n) return;
    float acc = 0.f;
    int beg = rowptr[i], end = rowptr[i + 1];
    int e = beg;
    for (; e + 3 < end; e += 4) {
        acc += (t[colarr[e]] + t[colarr[e + 1]]) + (t[colarr[e + 2]] + t[colarr[e + 3]]);
    }
    for (; e < end; ++e) acc += t[colarr[e]];
    s[i] = (acc + t[i]) * dinv[i] + b4[0];
}

// batch is sorted: record each graph's node range
__global__ void bounds_kernel(const int* __restrict__ batch, int* __restrict__ gstart,
                              int* __restrict__ gend, int n) {
    int i = blockIdx.x * 256 + threadIdx.x;
    if (i >= n) return;
    int g = batch[i];
    if (i == 0     || batch[i - 1] != g) gstart[g] = i;
    if (i == n - 1 || batch[i + 1] != g) gend[g]   = i + 1;
}

// one wave per graph: mean over its node range + sigmoid, straight to d_out
__global__ void pool2_kernel(const float* __restrict__ sv, const int* __restrict__ gstart,
                             const int* __restrict__ gend, float* __restrict__ out, int ng) {
    int g = blockIdx.x * 4 + (threadIdx.x >> 6);
    if (g >= ng) return;
    int lane = threadIdx.x & 63;
    int beg = gstart[g], end = gend[g];
    float acc = 0.f;
    for (int i = beg + lane; i < end; i += 64) acc += sv[i];
    #pragma unroll
    for (int off = 32; off; off >>= 1) acc += __shfl_xor(acc, off);
    if (lane == 0) {
        float c = fmaxf((float)(end - beg), 1.0f);
        float v = acc / c;
        out[g] = 1.0f / (1.0f + expf(-v));
    }
}

extern "C" void kernel_launch(void* const* d_in, const int* in_sizes, int n_in,
                              void* d_out, int out_size, void* d_ws, size_t ws_size,
                              hipStream_t stream) {
    const float* x    = (const float*)d_in[0];
    const int*   eidx = (const int*)d_in[1];
    const int*   batch= (const int*)d_in[2];
    const float* W1 = (const float*)d_in[3];
    const float* b1 = (const float*)d_in[4];
    const float* W2 = (const float*)d_in[5];
    const float* b2 = (const float*)d_in[6];
    const float* W3 = (const float*)d_in[7];
    const float* b3 = (const float*)d_in[8];
    const float* W4 = (const float*)d_in[9];
    const float* b4 = (const float*)d_in[10];

    const int n  = in_sizes[0] / 6;
    const int e  = in_sizes[1] / 2;
    const int ng = out_size;
    const int* src = eidx;
    const int* dst = eidx + e;

    // workspace layout
    char* ws = (char*)d_ws;
    float* bufA   = (float*)ws; ws += (size_t)n * 128 * 4;
    float* bufB   = (float*)ws; ws += (size_t)n * 128 * 4;
    int*   colarr = (int*)ws;   ws += (size_t)e * 4;
    int*   rowptr = (int*)ws;   ws += ((size_t)n + 4) * 4;
    float* dinv   = (float*)ws; ws += (size_t)n * 4;
    int*   counts = (int*)ws;   ws += (size_t)n * 4;   // later reused as t
    int*   cursor = (int*)ws;   ws += (size_t)n * 4;   // later reused as s
    int*   gstart = (int*)ws;   ws += 1024;
    int*   gend   = (int*)ws;   ws += 1024;

    float* xs = bufA;            // [n,6] prescaled x (bufA until gemm1 writes h1)
    float* ax = bufB;            // [n,6] aggregated (bufB until gemm1 consumes it)
    float* t  = (float*)counts;  // [n] after CSR build
    float* sv = (float*)cursor;  // [n] after CSR build

    const int eb = (e + 255) / 256;
    const int nb = (n + 255) / 256;
    const int nw = (n + 3) / 4;       // wave-per-node kernels, 4 waves/block
    const int gb = (n + GN - 1) / GN; // gemm128_reg blocks

    // ---- CSR build ----
    hipMemsetAsync(counts, 0, (size_t)n * 4, stream);
    hist_kernel<<<eb, 256, 0, stream>>>(dst, counts, e);
    dinv_kernel<<<nb, 256, 0, stream>>>(counts, dinv, n);
    scan_kernel<<<1, 1024, 0, stream>>>(counts, rowptr, n);
    hipMemsetAsync(cursor, 0, (size_t)n * 4, stream);
    scatter_kernel<<<eb, 256, 0, stream>>>(src, dst, rowptr, cursor, colarr, e);

    // ---- layer 1: prescale x, aggregate (6-dim), then GEMM ----
    xscale_kernel<<<(n * 6 + 255) / 256, 256, 0, stream>>>(x, dinv, xs, n);
    aggx_kernel<<<nb, 256, 0, stream>>>(xs, rowptr, colarr, dinv, ax, n);
    gemm1_kernel<<<(n * 128 + 255) / 256, 256, 0, stream>>>(ax, W1, b1, bufA, n);

    // ---- layer 2 ----
    gemm128_reg<<<gb, 256, 0, stream>>>(bufA, W2, dinv, bufB, n);
    agg128_kernel<<<nw, 256, 0, stream>>>(bufB, rowptr, colarr, dinv, b2, bufA, n, 1);

    // ---- layer 3 ----
    gemm128_reg<<<gb, 256, 0, stream>>>(bufA, W3, dinv, bufB, n);
    agg128_kernel<<<nw, 256, 0, stream>>>(bufB, rowptr, colarr, dinv, b3, bufA, n, 1);

    // ---- layer 4: project to scalar, aggregate ----
    head_kernel<<<nw, 256, 0, stream>>>(bufA, W4, dinv, t, n);
    aggs_kernel<<<nb, 256, 0, stream>>>(t, rowptr, colarr, dinv, b4, sv, n);

    // ---- pool: sorted batch -> segment bounds + per-graph wave mean ----
    hipMemsetAsync(gstart, 0, 2048, stream);  // covers gstart+gend (empty graphs -> [0,0))
    bounds_kernel<<<nb, 256, 0, stream>>>(batch, gstart, gend, n);
    pool2_kernel<<<(ng + 3) / 4, 256, 0, stream>>>(sv, gstart, gend, (float*)d_out, ng);
}

// Round 4
// 562.368 us; speedup vs baseline: 2.4963x; 1.2373x over previous
//
#include <hip/hip_runtime.h>
#include <math.h>

// ---------------------------------------------------------------------------
// SimpleGNN (4-layer GCN + mean pool + sigmoid) on MI355X.
//   - CSR build per call, XCD-affine sliced: slice = blockIdx&7 matches the
//     round-robin block->XCD dispatch, so each slice's 800KB colarr region is
//     assembled in ONE XCD's L2 -> single eviction (R3: 107MB HBM writes for
//     a 6.4MB array, 16x amplification from cross-XCD partial lines)
//   - norm factored into GEMM epilogue; aggregation = pure gather-sum
//   - layers 2,3: register-tiled f32 GEMM -> bf16 gather buffer (halves the
//     819MB/layer gather traffic; f32 accumulate)
//   - layer1 reassociated (aggregate 6-dim x first); layer4 projected to
//     scalar first; pool via sorted-batch segment bounds + wave reduce
// ---------------------------------------------------------------------------

#define NSLICE 8
#define BPS 128   // blocks per slice

__global__ void hist_sliced(const int* __restrict__ dst, int* __restrict__ counts,
                            int e, int ssz) {
    const int p   = blockIdx.x & (NSLICE - 1);
    const int blk = blockIdx.x >> 3;
    const int lo = p * ssz, hi = lo + ssz;
    const int per = (e + BPS - 1) / BPS;
    const int beg = blk * per;
    const int end = min(beg + per, e);
    for (int i = beg + threadIdx.x; i < end; i += 256) {
        int d = dst[i];
        if (d >= lo && d < hi) atomicAdd(&counts[d], 1);
    }
}

__global__ void scatter_sliced(const int* __restrict__ src, const int* __restrict__ dst,
                               const int* __restrict__ rowptr, int* __restrict__ cursor,
                               int* __restrict__ colarr, int e, int ssz) {
    const int p   = blockIdx.x & (NSLICE - 1);
    const int blk = blockIdx.x >> 3;
    const int lo = p * ssz, hi = lo + ssz;
    const int per = (e + BPS - 1) / BPS;
    const int beg = blk * per;
    const int end = min(beg + per, e);
    for (int i = beg + threadIdx.x; i < end; i += 256) {
        int d = dst[i];
        if (d >= lo && d < hi) {
            int pos = rowptr[d] + atomicAdd(&cursor[d], 1);
            colarr[pos] = src[i];
        }
    }
}

__global__ void dinv_kernel(const int* __restrict__ counts, float* __restrict__ dinv, int n) {
    int i = blockIdx.x * 256 + threadIdx.x;
    if (i < n) dinv[i] = rsqrtf((float)counts[i] + 1.0f);
}

// single-block chunked exclusive scan, 4 items/thread (chunk = 4096)
__global__ void scan_kernel(const int* __restrict__ counts, int* __restrict__ rowptr, int n) {
    __shared__ int wsum[16];
    __shared__ int carry_s;
    const int tid  = threadIdx.x;            // 1024 threads
    const int lane = tid & 63, wid = tid >> 6;
    if (tid == 0) carry_s = 0;
    __syncthreads();
    const int nchunk = (n + 4095) >> 12;
    for (int c = 0; c < nchunk; ++c) {
        int i0 = (c << 12) + tid * 4;
        int4 v = make_int4(0, 0, 0, 0);
        if (i0 + 3 < n) {
            v = *(const int4*)(counts + i0);
        } else {
            if (i0     < n) v.x = counts[i0];
            if (i0 + 1 < n) v.y = counts[i0 + 1];
            if (i0 + 2 < n) v.z = counts[i0 + 2];
            if (i0 + 3 < n) v.w = counts[i0 + 3];
        }
        int s1 = v.x, s2 = s1 + v.y, s3 = s2 + v.z, s4 = s3 + v.w;
        int x = s4;
        #pragma unroll
        for (int off = 1; off < 64; off <<= 1) {
            int y = __shfl_up(x, off);
            if (lane >= off) x += y;
        }
        if (lane == 63) wsum[wid] = x;
        __syncthreads();
        if (wid == 0) {
            int s = (lane < 16) ? wsum[lane] : 0;
            #pragma unroll
            for (int off = 1; off < 16; off <<= 1) {
                int y = __shfl_up(s, off);
                if (lane >= off) s += y;
            }
            if (lane < 16) wsum[lane] = s;
        }
        __syncthreads();
        int carry = carry_s + ((wid > 0) ? wsum[wid - 1] : 0);
        int excl  = carry + x - s4;   // exclusive prefix for this thread's items
        if (i0     < n) rowptr[i0 + 1] = excl + s1;
        if (i0 + 1 < n) rowptr[i0 + 2] = excl + s2;
        if (i0 + 2 < n) rowptr[i0 + 3] = excl + s3;
        if (i0 + 3 < n) rowptr[i0 + 4] = excl + s4;
        __syncthreads();
        if (tid == 1023) carry_s = carry + x;
        __syncthreads();
    }
    if (tid == 0) rowptr[0] = 0;
}

// xs[i,c] = x[i,c] * dinv[i]
__global__ void xscale_kernel(const float* __restrict__ x, const float* __restrict__ dinv,
                              float* __restrict__ xs, int n) {
    int i = blockIdx.x * 256 + threadIdx.x;
    if (i >= n * 6) return;
    xs[i] = x[i] * dinv[i / 6];
}

// ax[i] = dinv[i] * ( sum_{s in N(i)} xs[s] + xs[i] )    (6-dim)
__global__ void aggx_kernel(const float* __restrict__ xs, const int* __restrict__ rowptr,
                            const int* __restrict__ colarr, const float* __restrict__ dinv,
                            float* __restrict__ ax, int n) {
    int i = blockIdx.x * 256 + threadIdx.x;
    if (i >= n) return;
    float a0 = 0, a1 = 0, a2 = 0, a3 = 0, a4 = 0, a5 = 0;
    int beg = rowptr[i], end = rowptr[i + 1];
    for (int e = beg; e < end; ++e) {
        int s = colarr[e];
        const float* xr = xs + (size_t)s * 6;
        a0 += xr[0]; a1 += xr[1]; a2 += xr[2];
        a3 += xr[3]; a4 += xr[4]; a5 += xr[5];
    }
    const float* xi = xs + (size_t)i * 6;
    float di = dinv[i];
    float* o = ax + (size_t)i * 6;
    o[0] = (a0 + xi[0]) * di;
    o[1] = (a1 + xi[1]) * di;
    o[2] = (a2 + xi[2]) * di;
    o[3] = (a3 + xi[3]) * di;
    o[4] = (a4 + xi[4]) * di;
    o[5] = (a5 + xi[5]) * di;
}

// h1 = relu(ax @ W1 + b1)   (6 -> 128); thread = one (node, col)
__global__ __launch_bounds__(256) void gemm1_kernel(const float* __restrict__ ax,
                                                    const float* __restrict__ W1,
                                                    const float* __restrict__ b1,
                                                    float* __restrict__ h1, int n) {
    __shared__ float Wl[6 * 128];
    __shared__ float bl[128];
    for (int i = threadIdx.x; i < 6 * 128; i += 256) Wl[i] = W1[i];
    if (threadIdx.x < 128) bl[threadIdx.x] = b1[threadIdx.x];
    __syncthreads();
    int gid = blockIdx.x * 256 + threadIdx.x;
    int node = gid >> 7, c = gid & 127;
    if (node >= n) return;
    const float* ar = ax + (size_t)node * 6;
    float acc = bl[c];
    #pragma unroll
    for (int k = 0; k < 6; ++k) acc += ar[k] * Wl[k * 128 + c];
    h1[(size_t)node * 128 + c] = fmaxf(acc, 0.0f);
}

// round-to-nearest-even f32 -> bf16
__device__ __forceinline__ unsigned short f2bf(float f) {
    unsigned u = __float_as_uint(f);
    return (unsigned short)((u + 0x7fffu + ((u >> 16) & 1u)) >> 16);
}
__device__ __forceinline__ float bf2f(unsigned short b) {
    return __uint_as_float((unsigned)b << 16);
}

// gout[node,:] = bf16( (h[node,:] @ W) * dinv[node] )
// register-tiled: 64 nodes/block, 256 threads, each 8 nodes x 4 cols
#define GN 64
__global__ __launch_bounds__(256, 4) void gemm128_reg(const float* __restrict__ h,
                                                      const float* __restrict__ W,
                                                      const float* __restrict__ dinv,
                                                      unsigned short* __restrict__ gout, int n) {
    __shared__ float Hs[GN][132];   // +4 pad: 16B-aligned rows, conflict-free reads
    const int node0 = blockIdx.x * GN;
    {
        int r  = threadIdx.x >> 5;
        int c4 = (threadIdx.x & 31) * 4;
        #pragma unroll
        for (int rr = r; rr < GN; rr += 8) {
            int node = node0 + rr;
            float4 v = make_float4(0.f, 0.f, 0.f, 0.f);
            if (node < n) v = *(const float4*)(h + (size_t)node * 128 + c4);
            *(float4*)&Hs[rr][c4] = v;
        }
    }
    __syncthreads();
    const int tx = threadIdx.x & 31;   // col group: cols 4*tx .. 4*tx+3
    const int ty = threadIdx.x >> 5;   // node group: nodes ty*8 .. ty*8+7
    float4 acc[8];
    #pragma unroll
    for (int i = 0; i < 8; ++i) acc[i] = make_float4(0.f, 0.f, 0.f, 0.f);
    const float4* Wv = (const float4*)W;   // W row k, col group tx -> Wv[k*32+tx]
    #pragma unroll 4
    for (int k4 = 0; k4 < 32; ++k4) {
        float4 w0 = Wv[(4 * k4 + 0) * 32 + tx];
        float4 w1 = Wv[(4 * k4 + 1) * 32 + tx];
        float4 w2 = Wv[(4 * k4 + 2) * 32 + tx];
        float4 w3 = Wv[(4 * k4 + 3) * 32 + tx];
        #pragma unroll
        for (int i = 0; i < 8; ++i) {
            float4 hv = *(const float4*)&Hs[ty * 8 + i][4 * k4];
            acc[i].x += hv.x * w0.x + hv.y * w1.x + hv.z * w2.x + hv.w * w3.x;
            acc[i].y += hv.x * w0.y + hv.y * w1.y + hv.z * w2.y + hv.w * w3.y;
            acc[i].z += hv.x * w0.z + hv.y * w1.z + hv.z * w2.z + hv.w * w3.z;
            acc[i].w += hv.x * w0.w + hv.y * w1.w + hv.z * w2.w + hv.w * w3.w;
        }
    }
    #pragma unroll
    for (int i = 0; i < 8; ++i) {
        int node = node0 + ty * 8 + i;
        if (node < n) {
            float dv = dinv[node];
            ushort4 o;
            o.x = f2bf(acc[i].x * dv);
            o.y = f2bf(acc[i].y * dv);
            o.z = f2bf(acc[i].z * dv);
            o.w = f2bf(acc[i].w * dv);
            *(ushort4*)(gout + (size_t)node * 128 + 4 * tx) = o;
        }
    }
}

// out[i] = relu_opt( dinv[i]*( sum_{s in N(i)} g[s] + g[i] ) + b )   (128-dim, g is bf16)
__global__ __launch_bounds__(256) void agg128_kernel(const unsigned short* __restrict__ g,
                                                     const int* __restrict__ rowptr,
                                                     const int* __restrict__ colarr,
                                                     const float* __restrict__ dinv,
                                                     const float* __restrict__ bias,
                                                     float* __restrict__ out, int n, int relu) {
    int node = blockIdx.x * 4 + (threadIdx.x >> 6);
    if (node >= n) return;
    const int lane = threadIdx.x & 63;
    const ushort2* gl = (const ushort2*)g + lane;   // row s -> gl[s*64], cols 2*lane..
    const int beg = rowptr[node], end = rowptr[node + 1];
    float ax = 0.f, ay = 0.f;
    int e = beg;
    for (; e + 3 < end; e += 4) {
        int s0 = colarr[e], s1 = colarr[e + 1], s2 = colarr[e + 2], s3 = colarr[e + 3];
        ushort2 v0 = gl[(size_t)s0 * 64];
        ushort2 v1 = gl[(size_t)s1 * 64];
        ushort2 v2 = gl[(size_t)s2 * 64];
        ushort2 v3 = gl[(size_t)s3 * 64];
        ax += (bf2f(v0.x) + bf2f(v1.x)) + (bf2f(v2.x) + bf2f(v3.x));
        ay += (bf2f(v0.y) + bf2f(v1.y)) + (bf2f(v2.y) + bf2f(v3.y));
    }
    for (; e < end; ++e) {
        ushort2 v = gl[(size_t)colarr[e] * 64];
        ax += bf2f(v.x); ay += bf2f(v.y);
    }
    ushort2 sv = gl[(size_t)node * 64];
    float2 b  = ((const float2*)bias)[lane];
    float di  = dinv[node];
    float ox = (ax + bf2f(sv.x)) * di + b.x;
    float oy = (ay + bf2f(sv.y)) * di + b.y;
    if (relu) { ox = fmaxf(ox, 0.f); oy = fmaxf(oy, 0.f); }
    ((float2*)(out + (size_t)node * 128))[lane] = make_float2(ox, oy);
}

// t[i] = dot(h[i,:], W4[:,0]) * dinv[i] ; one wave per node
__global__ void head_kernel(const float* __restrict__ h, const float* __restrict__ W4,
                            const float* __restrict__ dinv, float* __restrict__ t, int n) {
    int node = blockIdx.x * 4 + (threadIdx.x >> 6);
    if (node >= n) return;
    int lane = threadIdx.x & 63;
    float2 v = ((const float2*)(h + (size_t)node * 128))[lane];
    float2 w = ((const float2*)W4)[lane];
    float p = v.x * w.x + v.y * w.y;
    #pragma unroll
    for (int off = 32; off; off >>= 1) p += __shfl_xor(p, off);
    if (lane == 0) t[node] = p * dinv[node];
}

// s[i] = dinv[i]*( sum t[s] + t[i] ) + b4
__global__ void aggs_kernel(const float* __restrict__ t, const int* __restrict__ rowptr,
                            const int* __restrict__ colarr, const float* __restrict__ dinv,
                            const float* __restrict__ b4, float* __restrict__ s, int n) {
    int i = blockIdx.x * 256 + threadIdx.x;
    if (i >= n) return;
    float acc = 0.f;
    int beg = rowptr[i], end = rowptr[i + 1];
    int e = beg;
    for (; e + 3 < end; e += 4) {
        acc += (t[colarr[e]] + t[colarr[e + 1]]) + (t[colarr[e + 2]] + t[colarr[e + 3]]);
    }
    for (; e < end; ++e) acc += t[colarr[e]];
    s[i] = (acc + t[i]) * dinv[i] + b4[0];
}

// batch is sorted: record each graph's node range
__global__ void bounds_kernel(const int* __restrict__ batch, int* __restrict__ gstart,
                              int* __restrict__ gend, int n) {
    int i = blockIdx.x * 256 + threadIdx.x;
    if (i >= n) return;
    int g = batch[i];
    if (i == 0     || batch[i - 1] != g) gstart[g] = i;
    if (i == n - 1 || batch[i + 1] != g) gend[g]   = i + 1;
}

// one wave per graph: mean over its node range + sigmoid, straight to d_out
__global__ void pool2_kernel(const float* __restrict__ sv, const int* __restrict__ gstart,
                             const int* __restrict__ gend, float* __restrict__ out, int ng) {
    int g = blockIdx.x * 4 + (threadIdx.x >> 6);
    if (g >= ng) return;
    int lane = threadIdx.x & 63;
    int beg = gstart[g], end = gend[g];
    float acc = 0.f;
    for (int i = beg + lane; i < end; i += 64) acc += sv[i];
    #pragma unroll
    for (int off = 32; off; off >>= 1) acc += __shfl_xor(acc, off);
    if (lane == 0) {
        float c = fmaxf((float)(end - beg), 1.0f);
        float v = acc / c;
        out[g] = 1.0f / (1.0f + expf(-v));
    }
}

extern "C" void kernel_launch(void* const* d_in, const int* in_sizes, int n_in,
                              void* d_out, int out_size, void* d_ws, size_t ws_size,
                              hipStream_t stream) {
    const float* x    = (const float*)d_in[0];
    const int*   eidx = (const int*)d_in[1];
    const int*   batch= (const int*)d_in[2];
    const float* W1 = (const float*)d_in[3];
    const float* b1 = (const float*)d_in[4];
    const float* W2 = (const float*)d_in[5];
    const float* b2 = (const float*)d_in[6];
    const float* W3 = (const float*)d_in[7];
    const float* b3 = (const float*)d_in[8];
    const float* W4 = (const float*)d_in[9];
    const float* b4 = (const float*)d_in[10];

    const int n  = in_sizes[0] / 6;
    const int e  = in_sizes[1] / 2;
    const int ng = out_size;
    const int* src = eidx;
    const int* dst = eidx + e;
    const int ssz = (n + NSLICE - 1) / NSLICE;

    // workspace layout
    char* ws = (char*)d_ws;
    float* bufA   = (float*)ws; ws += (size_t)n * 128 * 4;
    unsigned short* gbuf = (unsigned short*)ws; ws += (size_t)n * 128 * 4; // bf16 uses half
    int*   colarr = (int*)ws;   ws += (size_t)e * 4;
    int*   rowptr = (int*)ws;   ws += ((size_t)n + 4) * 4;
    float* dinv   = (float*)ws; ws += (size_t)n * 4;
    int*   counts = (int*)ws;   ws += (size_t)n * 4;   // later reused as t
    int*   cursor = (int*)ws;   ws += (size_t)n * 4;   // later reused as s
    int*   gstart = (int*)ws;   ws += 1024;
    int*   gend   = (int*)ws;   ws += 1024;

    float* xs = bufA;            // [n,6] prescaled x (bufA until gemm1 writes h1)
    float* ax = (float*)gbuf;    // [n,6] aggregated (gbuf region until gemm1 consumes it)
    float* t  = (float*)counts;  // [n] after CSR build
    float* sv = (float*)cursor;  // [n] after CSR build

    const int eb = (e + 255) / 256;
    const int nb = (n + 255) / 256;
    const int nw = (n + 3) / 4;       // wave-per-node kernels, 4 waves/block
    const int gb = (n + GN - 1) / GN; // gemm128_reg blocks

    // ---- CSR build (XCD-affine sliced) ----
    hipMemsetAsync(counts, 0, (size_t)n * 4, stream);
    hist_sliced<<<NSLICE * BPS, 256, 0, stream>>>(dst, counts, e, ssz);
    dinv_kernel<<<nb, 256, 0, stream>>>(counts, dinv, n);
    scan_kernel<<<1, 1024, 0, stream>>>(counts, rowptr, n);
    hipMemsetAsync(cursor, 0, (size_t)n * 4, stream);
    scatter_sliced<<<NSLICE * BPS, 256, 0, stream>>>(src, dst, rowptr, cursor, colarr, e, ssz);

    // ---- layer 1: prescale x, aggregate (6-dim), then GEMM ----
    xscale_kernel<<<(n * 6 + 255) / 256, 256, 0, stream>>>(x, dinv, xs, n);
    aggx_kernel<<<nb, 256, 0, stream>>>(xs, rowptr, colarr, dinv, ax, n);
    gemm1_kernel<<<(n * 128 + 255) / 256, 256, 0, stream>>>(ax, W1, b1, bufA, n);

    // ---- layer 2 ----
    gemm128_reg<<<gb, 256, 0, stream>>>(bufA, W2, dinv, gbuf, n);
    agg128_kernel<<<nw, 256, 0, stream>>>(gbuf, rowptr, colarr, dinv, b2, bufA, n, 1);

    // ---- layer 3 ----
    gemm128_reg<<<gb, 256, 0, stream>>>(bufA, W3, dinv, gbuf, n);
    agg128_kernel<<<nw, 256, 0, stream>>>(gbuf, rowptr, colarr, dinv, b3, bufA, n, 1);

    // ---- layer 4: project to scalar, aggregate ----
    head_kernel<<<nw, 256, 0, stream>>>(bufA, W4, dinv, t, n);
    aggs_kernel<<<nb, 256, 0, stream>>>(t, rowptr, colarr, dinv, b4, sv, n);

    // ---- pool: sorted batch -> segment bounds + per-graph wave mean ----
    hipMemsetAsync(gstart, 0, 2048, stream);  // covers gstart+gend (empty graphs -> [0,0))
    bounds_kernel<<<nb, 256, 0, stream>>>(batch, gstart, gend, n);
    pool2_kernel<<<(ng + 3) / 4, 256, 0, stream>>>(sv, gstart, gend, (float*)d_out, ng);
}